// Round 6
// baseline (1085.888 us; speedup 1.0000x reference)
//
#include <hip/hip_runtime.h>

#define KAPPA 0.95f

typedef __attribute__((ext_vector_type(8))) short short8;
typedef __attribute__((ext_vector_type(4))) float f32x4;

// ---------- bf16 helpers ----------
static __device__ inline unsigned short f2bf(float f) {
    unsigned int u = __float_as_uint(f);
    unsigned int rounding = 0x7fffu + ((u >> 16) & 1u);
    u += rounding;
    return (unsigned short)(u >> 16);
}
static __device__ inline unsigned int pack2bf(float x, float y) {
    return (unsigned int)f2bf(x) | ((unsigned int)f2bf(y) << 16);
}
static __device__ inline float bflo(unsigned int u) { return __uint_as_float(u << 16); }
static __device__ inline float bfhi(unsigned int u) { return __uint_as_float(u & 0xffff0000u); }

// ---------- 1. proj_norm_inf on W_conv -> bf16 row-major [c][k] ----------
__global__ __launch_bounds__(128) void proj_kernel(const float* __restrict__ W,
                                                   unsigned short* __restrict__ Wp_bf) {
    const int r = blockIdx.x;
    const int tid = threadIdx.x;
    __shared__ float s[128];
    __shared__ float c[128];
    __shared__ int rho_s;

    const float w = W[r * 128 + tid];
    const float a = fabsf(w);
    s[tid] = a;
    if (tid == 0) rho_s = 0;
    __syncthreads();

    for (int k = 2; k <= 128; k <<= 1) {
        for (int j = k >> 1; j > 0; j >>= 1) {
            int ixj = tid ^ j;
            if (ixj > tid) {
                bool up = ((tid & k) == 0);
                float x = s[tid], y = s[ixj];
                if ((x > y) == up) { s[tid] = y; s[ixj] = x; }
            }
            __syncthreads();
        }
    }

    const float u = s[127 - tid];
    c[tid] = u;
    __syncthreads();
    for (int off = 1; off < 128; off <<= 1) {
        float add = (tid >= off) ? c[tid - off] : 0.f;
        __syncthreads();
        c[tid] += add;
        __syncthreads();
    }
    const float rowsum = c[127];
    const float css = c[tid] - KAPPA;
    if (u - css / (float)(tid + 1) > 0.f) atomicAdd(&rho_s, 1);
    __syncthreads();

    float out = w;
    if (rowsum > KAPPA) {
        int rho = max(rho_s, 1);
        float theta = (c[rho - 1] - KAPPA) / (float)rho;
        float m = fmaxf(a - theta, 0.f);
        out = (w > 0.f) ? m : ((w < 0.f) ? -m : 0.f);
    }
    Wp_bf[r * 128 + tid] = f2bf(out);  // row-major [c][k]
}

// ---------- 2. W_mlp f32 -> bf16 ----------
__global__ void convw_kernel(const float* __restrict__ Wm, unsigned short* __restrict__ Wbf,
                             int n) {
    int i = blockIdx.x * blockDim.x + threadIdx.x;
    if (i < n) Wbf[i] = f2bf(Wm[i]);
}

// ---------- 3a. per-block bucket counts (8 dst-range buckets), atomic-free ----------
__global__ __launch_bounds__(64) void qcount_kernel(const int* __restrict__ dst,
                                                    int* __restrict__ bc, int E, float qscale,
                                                    int chunk, int nbp) {
    const int b = blockIdx.x, lane = threadIdx.x;
    const int i0 = b * chunk;
    const int i1 = min(i0 + chunk, E);
    const int len = max(0, i1 - i0);
    const int nit = (len + 63) >> 6;
    int cnt[8];
#pragma unroll
    for (int k = 0; k < 8; ++k) cnt[k] = 0;
    for (int it = 0; it < nit; ++it) {
        int i = i0 + it * 64 + lane;
        int q = 8;
        if (i < i1) q = min(7, (int)((float)dst[i] * qscale));
#pragma unroll
        for (int k = 0; k < 8; ++k) cnt[k] += (int)__popcll(__ballot(q == k));
    }
    if (lane == 0) {
#pragma unroll
        for (int k = 0; k < 8; ++k) bc[k * nbp + b] = cnt[k];
    }
}

// generic single-block chunked exclusive scan
__global__ __launch_bounds__(1024) void scan_kernel(const int* __restrict__ in,
                                                    int* __restrict__ out, int n) {
    __shared__ int tmp[1024];
    __shared__ int carry;
    const int tid = threadIdx.x;
    if (tid == 0) carry = 0;
    __syncthreads();
    for (int base = 0; base < n; base += 1024) {
        int i = base + tid;
        int v = (i < n) ? in[i] : 0;
        tmp[tid] = v;
        __syncthreads();
        int val = v;
        for (int off = 1; off < 1024; off <<= 1) {
            int add = (tid >= off) ? tmp[tid - off] : 0;
            __syncthreads();
            val += add;
            tmp[tid] = val;
            __syncthreads();
        }
        if (i < n) out[i] = carry + val - v;
        int total = tmp[1023];
        __syncthreads();
        if (tid == 0) carry += total;
    }
}

// ---------- 3b. partition edges into 8 dst-range queues, atomic-free ----------
__global__ __launch_bounds__(64) void qpart_kernel(const int* __restrict__ src,
                                                   const int* __restrict__ dst,
                                                   const int* __restrict__ bbase,
                                                   uint2* __restrict__ queue, int E, float qscale,
                                                   int chunk, int nbp) {
    const int b = blockIdx.x, lane = threadIdx.x;
    int base[8];
#pragma unroll
    for (int k = 0; k < 8; ++k) base[k] = bbase[k * nbp + b];
    const int i0 = b * chunk;
    const int i1 = min(i0 + chunk, E);
    const int len = max(0, i1 - i0);
    const int nit = (len + 63) >> 6;
    const unsigned long long ltm = (1ull << lane) - 1ull;
    for (int it = 0; it < nit; ++it) {
        int i = i0 + it * 64 + lane;
        int s = 0, d = 0, q = 8;
        if (i < i1) {
            s = src[i];
            d = dst[i];
            q = min(7, (int)((float)d * qscale));
        }
#pragma unroll
        for (int k = 0; k < 8; ++k) {
            unsigned long long m = __ballot(q == k);
            if (q == k) {
                int rank = (int)__popcll(m & ltm);
                queue[base[k] + rank] = make_uint2((unsigned)s, (unsigned)d);
            }
            base[k] += (int)__popcll(m);
        }
    }
}

// ---------- 3c. node-range-owned count: LDS histogram, contiguous writes ----------
// grid 256 x 1024. Logical block L = (B%8)*32 + B/8 so L/32 == XCD == dst bucket.
__global__ __launch_bounds__(1024) void countv2_kernel(const uint2* __restrict__ queue,
                                                       const int* __restrict__ bbase,
                                                       int* __restrict__ counts, int n, int E,
                                                       float qscale, int nbpv) {
    __shared__ int hist[400];
    const int B = blockIdx.x;
    const int L = (B & 7) * 32 + (B >> 3);
    const int npb = (n + 255) / 256;
    const int v0 = L * npb;
    const int v1 = min(v0 + npb, n);
    if (v0 >= n) return;
    for (int t = threadIdx.x; t < npb; t += 1024) hist[t] = 0;
    __syncthreads();
    const int q0 = min(7, (int)((float)v0 * qscale));
    const int q1 = min(7, (int)((float)(v1 - 1) * qscale));
    const int s = bbase[q0 * nbpv];
    const int e = (q1 == 7) ? E : bbase[(q1 + 1) * nbpv];
    const unsigned long long* qp = reinterpret_cast<const unsigned long long*>(queue);
    for (int i = s + threadIdx.x; i < e; i += 1024) {
        unsigned long long raw = __builtin_nontemporal_load(qp + i);
        int d = (int)(unsigned int)(raw >> 32);
        if (d >= v0 && d < v1) atomicAdd(&hist[d - v0], 1);
    }
    __syncthreads();
    for (int t = threadIdx.x; t < v1 - v0; t += 1024) counts[v0 + t] = hist[t];
}

// ---------- 3d. per-node scan: counts -> cursor (exclusive) + dinv ----------
__global__ __launch_bounds__(1024) void scan1_kernel(const int* __restrict__ counts,
                                                     int* __restrict__ partials, int n) {
    __shared__ int tmp[1024];
    int i = blockIdx.x * 1024 + threadIdx.x;
    tmp[threadIdx.x] = (i < n) ? counts[i] : 0;
    __syncthreads();
    for (int off = 512; off > 0; off >>= 1) {
        if (threadIdx.x < off) tmp[threadIdx.x] += tmp[threadIdx.x + off];
        __syncthreads();
    }
    if (threadIdx.x == 0) partials[blockIdx.x] = tmp[0];
}

__global__ __launch_bounds__(1024) void scan2_kernel(int* __restrict__ partials, int nb) {
    __shared__ int tmp[1024];
    const int tid = threadIdx.x;
    int v = (tid < nb) ? partials[tid] : 0;
    tmp[tid] = v;
    __syncthreads();
    int val = v;
    for (int off = 1; off < 1024; off <<= 1) {
        int add = (tid >= off) ? tmp[tid - off] : 0;
        __syncthreads();
        val += add;
        tmp[tid] = val;
        __syncthreads();
    }
    if (tid < nb) partials[tid] = val - v;
}

__global__ __launch_bounds__(1024) void scan3_kernel(const int* __restrict__ counts,
                                                     const int* __restrict__ partials,
                                                     int* __restrict__ cursor,
                                                     float* __restrict__ dinv, int n) {
    __shared__ int tmp[1024];
    const int tid = threadIdx.x;
    int i = blockIdx.x * 1024 + tid;
    int v = (i < n) ? counts[i] : 0;
    tmp[tid] = v;
    __syncthreads();
    int val = v;
    for (int off = 1; off < 1024; off <<= 1) {
        int add = (tid >= off) ? tmp[tid - off] : 0;
        __syncthreads();
        val += add;
        tmp[tid] = val;
        __syncthreads();
    }
    if (i < n) {
        cursor[i] = partials[blockIdx.x] + val - v;
        dinv[i] = rsqrtf((float)(v + 1));
    }
}

// ---------- 3e. edge-balanced LDS-staged CSR fill: contiguous writes ----------
// Block L owns nodes {v : cursor[v] in [L*S,(L+1)*S)}; stages its csr slice in
// LDS via LDS cursors, then writes it out contiguously. cursor is NOT mutated.
__global__ __launch_bounds__(1024) void fillv2_kernel(const uint2* __restrict__ queue,
                                                      const int* __restrict__ bbase,
                                                      const int* __restrict__ cursor,
                                                      int* __restrict__ csr_src, int n, int E,
                                                      float qscale, int nbpv, int S) {
    __shared__ int stage[12608];
    __shared__ int lofs[1024];
    __shared__ int lcnt[1024];
    const int B = blockIdx.x;
    const int L = (B & 7) * 32 + (B >> 3);
    const int x0 = L * S;
    if (x0 >= E) return;
    const int x1 = x0 + S;

    // lower_bound over cursor (all threads compute redundantly)
    int lo = 0, hi = n;
    while (lo < hi) { int mid = (lo + hi) >> 1; if (cursor[mid] < x0) lo = mid + 1; else hi = mid; }
    const int v0 = lo;
    hi = n;
    while (lo < hi) { int mid = (lo + hi) >> 1; if (cursor[mid] < x1) lo = mid + 1; else hi = mid; }
    const int v1 = lo;
    if (v0 >= n || v1 == v0) {
        // still may have zero nodes; nothing to write
        if (v0 >= n) return;
    }
    const int base = cursor[v0];
    const int tot = ((v1 < n) ? cursor[v1] : E) - base;
    const int nn = v1 - v0;
    for (int t = threadIdx.x; t < nn; t += 1024) {
        lofs[t] = cursor[v0 + t] - base;
        lcnt[t] = 0;
    }
    __syncthreads();
    if (tot > 0) {
        const int vq = (v1 - 1 > v0) ? v1 - 1 : v0;
        const int q0 = min(7, (int)((float)v0 * qscale));
        const int q1 = min(7, (int)((float)vq * qscale));
        const int s = bbase[q0 * nbpv];
        const int e = (q1 == 7) ? E : bbase[(q1 + 1) * nbpv];
        const unsigned long long* qp = reinterpret_cast<const unsigned long long*>(queue);
        for (int i = s + threadIdx.x; i < e; i += 1024) {
            unsigned long long raw = __builtin_nontemporal_load(qp + i);
            int d = (int)(unsigned int)(raw >> 32);
            if (d >= v0 && d < v1) {
                int p = atomicAdd(&lcnt[d - v0], 1);
                stage[lofs[d - v0] + p] = (int)(unsigned int)raw;
            }
        }
    }
    __syncthreads();
    for (int i = threadIdx.x; i < tot; i += 1024) csr_src[base + i] = stage[i];
}

// ---------- 4. MFMA GEMM: out = X[nrows,KD](f32) @ Wbf[c][k](bf16).T ----------
template <int KD, int MODE>
__global__ __launch_bounds__(256) void gemm_mfma(const float* __restrict__ X,
                                                 const unsigned short* __restrict__ Wbf,
                                                 const float* __restrict__ dinv,
                                                 const float* ADD,
                                                 unsigned short* __restrict__ out_bf,
                                                 float* out_f, int nrows) {
    __shared__ __align__(16) unsigned short ldsX[128 * 40];
    const int tid = threadIdx.x;
    const int w = tid >> 6;
    const int l = tid & 63;
    const int l16 = l & 15;
    const int kg = l >> 4;
    const int row0 = blockIdx.x * 128;

    f32x4 acc[2][8];
#pragma unroll
    for (int i = 0; i < 2; ++i)
#pragma unroll
        for (int j = 0; j < 8; ++j) acc[i][j] = (f32x4)(0.f);

    const int srow = tid >> 1;
    const int rload = min(row0 + srow, nrows - 1);
    const int kk0 = (tid & 1) * 16;
    const float* xrow = X + (size_t)rload * KD + kk0;

    for (int k0 = 0; k0 < KD; k0 += 32) {
        __syncthreads();
        {
            const float4* xs = reinterpret_cast<const float4*>(xrow + k0);
            float4 v0 = xs[0], v1 = xs[1], v2 = xs[2], v3 = xs[3];
            uint4 pa, pb;
            pa.x = pack2bf(v0.x, v0.y); pa.y = pack2bf(v0.z, v0.w);
            pa.z = pack2bf(v1.x, v1.y); pa.w = pack2bf(v1.z, v1.w);
            pb.x = pack2bf(v2.x, v2.y); pb.y = pack2bf(v2.z, v2.w);
            pb.z = pack2bf(v3.x, v3.y); pb.w = pack2bf(v3.z, v3.w);
            *reinterpret_cast<uint4*>(&ldsX[srow * 40 + kk0]) = pa;
            *reinterpret_cast<uint4*>(&ldsX[srow * 40 + kk0 + 8]) = pb;
        }
        __syncthreads();

        short8 a0 = *reinterpret_cast<const short8*>(&ldsX[(w * 32 + l16) * 40 + kg * 8]);
        short8 a1 = *reinterpret_cast<const short8*>(&ldsX[(w * 32 + 16 + l16) * 40 + kg * 8]);
#pragma unroll
        for (int ct = 0; ct < 8; ++ct) {
            short8 b = *reinterpret_cast<const short8*>(
                &Wbf[(size_t)(ct * 16 + l16) * KD + k0 + kg * 8]);
            acc[0][ct] = __builtin_amdgcn_mfma_f32_16x16x32_bf16(a0, b, acc[0][ct], 0, 0, 0);
            acc[1][ct] = __builtin_amdgcn_mfma_f32_16x16x32_bf16(a1, b, acc[1][ct], 0, 0, 0);
        }
    }

#pragma unroll
    for (int rt = 0; rt < 2; ++rt) {
        const int rbase = row0 + w * 32 + rt * 16 + kg * 4;
        float dv[4];
        if (MODE == 0) {
#pragma unroll
            for (int reg = 0; reg < 4; ++reg)
                dv[reg] = (rbase + reg < nrows) ? dinv[rbase + reg] : 0.f;
        }
#pragma unroll
        for (int ct = 0; ct < 8; ++ct) {
            const int col = ct * 16 + l16;
            f32x4 d = acc[rt][ct];
#pragma unroll
            for (int reg = 0; reg < 4; ++reg) {
                int r = rbase + reg;
                if (r < nrows) {
                    if (MODE == 0) {
                        out_bf[(size_t)r * 128 + col] = f2bf(d[reg] * dv[reg]);
                    } else {
                        float add = ADD[(size_t)r * 128 + col];
                        out_f[(size_t)r * 128 + col] = fmaxf(d[reg] + add, 0.f);
                    }
                }
            }
        }
    }
}

// ---------- 5. aggregation ----------
__global__ __launch_bounds__(256) void agg_kernel(const unsigned int* __restrict__ h,
                                                  const int* __restrict__ csr_src,
                                                  const int* __restrict__ cursor,
                                                  const int* __restrict__ counts,
                                                  const float* __restrict__ dinv,
                                                  float* __restrict__ agg, int n) {
    int v = blockIdx.x * 4 + (threadIdx.x >> 6);
    if (v >= n) return;
    const int lane = threadIdx.x & 63;
    const int eg = lane >> 4;
    const int c = lane & 15;
    const int cnt = counts[v];
    const int start = cursor[v];  // cursor is exclusive offsets (not mutated)

    const uint4* hp = reinterpret_cast<const uint4*>(h);
    float acc[8];
#pragma unroll
    for (int j = 0; j < 8; ++j) acc[j] = 0.f;

    int s_next = (eg < cnt) ? csr_src[start + eg] : -1;
    for (int base = 0; base < cnt; base += 4) {
        int s = s_next;
        int nx = base + 4 + eg;
        s_next = (nx < cnt) ? csr_src[start + nx] : -1;
        if (s >= 0) {
            uint4 val = hp[(size_t)s * 16 + c];
            acc[0] += bflo(val.x); acc[1] += bfhi(val.x);
            acc[2] += bflo(val.y); acc[3] += bfhi(val.y);
            acc[4] += bflo(val.z); acc[5] += bfhi(val.z);
            acc[6] += bflo(val.w); acc[7] += bfhi(val.w);
        }
    }
    if (eg == 0) {
        uint4 val = hp[(size_t)v * 16 + c];
        acc[0] += bflo(val.x); acc[1] += bfhi(val.x);
        acc[2] += bflo(val.y); acc[3] += bfhi(val.y);
        acc[4] += bflo(val.z); acc[5] += bfhi(val.z);
        acc[6] += bflo(val.w); acc[7] += bfhi(val.w);
    }
#pragma unroll
    for (int j = 0; j < 8; ++j) {
        acc[j] += __shfl_xor(acc[j], 16);
        acc[j] += __shfl_xor(acc[j], 32);
    }
    if (eg == 0) {
        float dv = dinv[v];
        float4 o0 = {acc[0] * dv, acc[1] * dv, acc[2] * dv, acc[3] * dv};
        float4 o1 = {acc[4] * dv, acc[5] * dv, acc[6] * dv, acc[7] * dv};
        *reinterpret_cast<float4*>(&agg[(size_t)v * 128 + c * 8]) = o0;
        *reinterpret_cast<float4*>(&agg[(size_t)v * 128 + c * 8 + 4]) = o1;
    }
}

// ---------- launch ----------
extern "C" void kernel_launch(void* const* d_in, const int* in_sizes, int n_in,
                              void* d_out, int out_size, void* d_ws, size_t ws_size,
                              hipStream_t stream) {
    const float* features = (const float*)d_in[0];
    const int*   edge     = (const int*)d_in[1];
    const float* emb      = (const float*)d_in[2];
    const float* Wconv    = (const float*)d_in[3];
    const float* Wmlp     = (const float*)d_in[4];
    float* out = (float*)d_out;

    const int N = in_sizes[0] / 256;
    const int E = in_sizes[1] / 2;
    const int* src = edge;
    const int* dst = edge + E;
    const int NB = (N + 1023) / 1024;
    const int NBP = 4096;                      // partition virtual blocks
    const int chunk = (E + NBP - 1) / NBP;
    const float qscale = 8.0f / (float)N;
    const int S = (E + 255) / 256;             // edges per fill block (12500)

    char* ws = (char*)d_ws;
    size_t o = 0;
    auto take = [&](size_t b) {
        size_t cur = o;
        o += (b + 255) & ~(size_t)255;
        return cur;
    };
    unsigned short* Wp_bf   = (unsigned short*)(ws + take((size_t)128 * 128 * 2));
    unsigned short* Wm_bf   = (unsigned short*)(ws + take((size_t)128 * 256 * 2));
    int*            counts  = (int*)(ws + take((size_t)N * 4));
    int*            cursor  = (int*)(ws + take((size_t)N * 4));
    float*          dinv    = (float*)(ws + take((size_t)N * 4));
    int*            partials= (int*)(ws + take((size_t)(NB + 1) * 4));
    int*            bc      = (int*)(ws + take((size_t)8 * NBP * 4));
    int*            bbase   = (int*)(ws + take((size_t)8 * NBP * 4));
    int*            csr_src = (int*)(ws + take((size_t)E * 4));
    size_t qbytes = (size_t)E * 8;
    size_t hbytes = (size_t)N * 128 * 2;
    char*  qh     = ws + take(qbytes > hbytes ? qbytes : hbytes);
    uint2*          queue = (uint2*)qh;
    unsigned short* hbuf  = (unsigned short*)qh;
    (void)ws_size; (void)n_in; (void)out_size;

    hipLaunchKernelGGL(proj_kernel, dim3(128), dim3(128), 0, stream, Wconv, Wp_bf);
    hipLaunchKernelGGL(convw_kernel, dim3((128 * 256 + 255) / 256), dim3(256), 0, stream, Wmlp,
                       Wm_bf, 128 * 256);
    hipLaunchKernelGGL(qcount_kernel, dim3(NBP), dim3(64), 0, stream, dst, bc, E, qscale, chunk,
                       NBP);
    hipLaunchKernelGGL(scan_kernel, dim3(1), dim3(1024), 0, stream, bc, bbase, 8 * NBP);
    hipLaunchKernelGGL(qpart_kernel, dim3(NBP), dim3(64), 0, stream, src, dst, bbase, queue, E,
                       qscale, chunk, NBP);
    // node-range-owned count (LDS hist, contiguous writes, no global atomics)
    hipLaunchKernelGGL(countv2_kernel, dim3(256), dim3(1024), 0, stream, queue, bbase, counts, N,
                       E, qscale, NBP);
    hipLaunchKernelGGL(scan1_kernel, dim3(NB), dim3(1024), 0, stream, counts, partials, N);
    hipLaunchKernelGGL(scan2_kernel, dim3(1), dim3(1024), 0, stream, partials, NB);
    hipLaunchKernelGGL(scan3_kernel, dim3(NB), dim3(1024), 0, stream, counts, partials, cursor,
                       dinv, N);
    // edge-balanced LDS-staged CSR fill (contiguous writes; cursor unchanged)
    hipLaunchKernelGGL(fillv2_kernel, dim3(256), dim3(1024), 0, stream, queue, bbase, cursor,
                       csr_src, N, E, qscale, NBP, S);
    // h' = bf16( dinv[row] * (emb @ Wp.T) )  -- overwrites queue storage
    hipLaunchKernelGGL((gemm_mfma<128, 0>), dim3((N + 127) / 128), dim3(256), 0, stream, emb,
                       Wp_bf, dinv, (const float*)nullptr, hbuf, (float*)nullptr, N);
    hipLaunchKernelGGL(agg_kernel, dim3((N + 3) / 4), dim3(256), 0, stream,
                       (const unsigned int*)hbuf, csr_src, cursor, counts, dinv, out, N);
    // out = relu(features @ Wmlp.T + agg)
    hipLaunchKernelGGL((gemm_mfma<256, 1>), dim3((N + 127) / 128), dim3(256), 0, stream, features,
                       Wm_bf, (const float*)nullptr, out, (unsigned short*)nullptr, out, N);
}

// Round 7
// 431.824 us; speedup vs baseline: 2.5147x; 2.5147x over previous
//
#include <hip/hip_runtime.h>

#define KAPPA 0.95f

typedef __attribute__((ext_vector_type(8))) short short8;
typedef __attribute__((ext_vector_type(4))) float f32x4;

// ---------- bf16 helpers ----------
static __device__ inline unsigned short f2bf(float f) {
    unsigned int u = __float_as_uint(f);
    unsigned int rounding = 0x7fffu + ((u >> 16) & 1u);
    u += rounding;
    return (unsigned short)(u >> 16);
}
static __device__ inline unsigned int pack2bf(float x, float y) {
    return (unsigned int)f2bf(x) | ((unsigned int)f2bf(y) << 16);
}
static __device__ inline float bflo(unsigned int u) { return __uint_as_float(u << 16); }
static __device__ inline float bfhi(unsigned int u) { return __uint_as_float(u & 0xffff0000u); }

// ---------- 1. proj_norm_inf on W_conv -> bf16 row-major [c][k] ----------
__global__ __launch_bounds__(128) void proj_kernel(const float* __restrict__ W,
                                                   unsigned short* __restrict__ Wp_bf) {
    const int r = blockIdx.x;
    const int tid = threadIdx.x;
    __shared__ float s[128];
    __shared__ float c[128];
    __shared__ int rho_s;

    const float w = W[r * 128 + tid];
    const float a = fabsf(w);
    s[tid] = a;
    if (tid == 0) rho_s = 0;
    __syncthreads();

    for (int k = 2; k <= 128; k <<= 1) {
        for (int j = k >> 1; j > 0; j >>= 1) {
            int ixj = tid ^ j;
            if (ixj > tid) {
                bool up = ((tid & k) == 0);
                float x = s[tid], y = s[ixj];
                if ((x > y) == up) { s[tid] = y; s[ixj] = x; }
            }
            __syncthreads();
        }
    }

    const float u = s[127 - tid];
    c[tid] = u;
    __syncthreads();
    for (int off = 1; off < 128; off <<= 1) {
        float add = (tid >= off) ? c[tid - off] : 0.f;
        __syncthreads();
        c[tid] += add;
        __syncthreads();
    }
    const float rowsum = c[127];
    const float css = c[tid] - KAPPA;
    if (u - css / (float)(tid + 1) > 0.f) atomicAdd(&rho_s, 1);
    __syncthreads();

    float out = w;
    if (rowsum > KAPPA) {
        int rho = max(rho_s, 1);
        float theta = (c[rho - 1] - KAPPA) / (float)rho;
        float m = fmaxf(a - theta, 0.f);
        out = (w > 0.f) ? m : ((w < 0.f) ? -m : 0.f);
    }
    Wp_bf[r * 128 + tid] = f2bf(out);  // row-major [c][k]
}

// ---------- 2. W_mlp f32 -> bf16 ----------
__global__ void convw_kernel(const float* __restrict__ Wm, unsigned short* __restrict__ Wbf,
                             int n) {
    int i = blockIdx.x * blockDim.x + threadIdx.x;
    if (i < n) Wbf[i] = f2bf(Wm[i]);
}

// ---------- 3a. level-1 bucket counts (8 dst-range buckets), ballot, atomic-free ----------
__global__ __launch_bounds__(64) void qcount_kernel(const int* __restrict__ dst,
                                                    int* __restrict__ bc, int E, unsigned N,
                                                    int chunk, int nbp) {
    const int b = blockIdx.x, lane = threadIdx.x;
    const int i0 = b * chunk;
    const int i1 = min(i0 + chunk, E);
    const int len = max(0, i1 - i0);
    const int nit = (len + 63) >> 6;
    int cnt[8];
#pragma unroll
    for (int k = 0; k < 8; ++k) cnt[k] = 0;
    for (int it = 0; it < nit; ++it) {
        int i = i0 + it * 64 + lane;
        int q = 8;
        if (i < i1) q = (int)(((unsigned)dst[i] * 8u) / N);
#pragma unroll
        for (int k = 0; k < 8; ++k) cnt[k] += (int)__popcll(__ballot(q == k));
    }
    if (lane == 0) {
#pragma unroll
        for (int k = 0; k < 8; ++k) bc[k * nbp + b] = cnt[k];
    }
}

// generic single-block chunked exclusive scan
__global__ __launch_bounds__(1024) void scan_kernel(const int* __restrict__ in,
                                                    int* __restrict__ out, int n) {
    __shared__ int tmp[1024];
    __shared__ int carry;
    const int tid = threadIdx.x;
    if (tid == 0) carry = 0;
    __syncthreads();
    for (int base = 0; base < n; base += 1024) {
        int i = base + tid;
        int v = (i < n) ? in[i] : 0;
        tmp[tid] = v;
        __syncthreads();
        int val = v;
        for (int off = 1; off < 1024; off <<= 1) {
            int add = (tid >= off) ? tmp[tid - off] : 0;
            __syncthreads();
            val += add;
            tmp[tid] = val;
            __syncthreads();
        }
        if (i < n) out[i] = carry + val - v;
        int total = tmp[1023];
        __syncthreads();
        if (tid == 0) carry += total;
    }
}

// ---------- 3b. level-1 partition into 8 dst-range queues, atomic-free ----------
__global__ __launch_bounds__(64) void qpart_kernel(const int* __restrict__ src,
                                                   const int* __restrict__ dst,
                                                   const int* __restrict__ bbase,
                                                   uint2* __restrict__ queue, int E, unsigned N,
                                                   int chunk, int nbp) {
    const int b = blockIdx.x, lane = threadIdx.x;
    int base[8];
#pragma unroll
    for (int k = 0; k < 8; ++k) base[k] = bbase[k * nbp + b];
    const int i0 = b * chunk;
    const int i1 = min(i0 + chunk, E);
    const int len = max(0, i1 - i0);
    const int nit = (len + 63) >> 6;
    const unsigned long long ltm = (1ull << lane) - 1ull;
    for (int it = 0; it < nit; ++it) {
        int i = i0 + it * 64 + lane;
        int s = 0, d = 0, q = 8;
        if (i < i1) {
            s = src[i];
            d = dst[i];
            q = (int)(((unsigned)d * 8u) / N);
        }
#pragma unroll
        for (int k = 0; k < 8; ++k) {
            unsigned long long m = __ballot(q == k);
            if (q == k) {
                int rank = (int)__popcll(m & ltm);
                queue[base[k] + rank] = make_uint2((unsigned)s, (unsigned)d);
            }
            base[k] += (int)__popcll(m);
        }
    }
}

// ---------- 3c. level-2 count: 64 sub-bins per (bucket q, chunk j) ----------
// grid 512: q = B&7 (XCD-owned), j = B>>3 in [0,64)
__global__ __launch_bounds__(256) void l2count_kernel(const uint2* __restrict__ queue,
                                                      const int* __restrict__ bbase,
                                                      int* __restrict__ l2c, unsigned N, int E,
                                                      int nbp) {
    __shared__ int hist[64];
    const int q = blockIdx.x & 7, j = blockIdx.x >> 3;
    const int bb0 = bbase[q * nbp];
    const int bb1 = (q == 7) ? E : bbase[(q + 1) * nbp];
    const int len = bb1 - bb0;
    const int cl = (len + 63) >> 6;
    const int c0 = min(bb0 + j * cl, bb1);
    const int c1 = min(c0 + cl, bb1);
    if (threadIdx.x < 64) hist[threadIdx.x] = 0;
    __syncthreads();
    const unsigned long long* qp = reinterpret_cast<const unsigned long long*>(queue);
    for (int i = c0 + threadIdx.x; i < c1; i += 256) {
        unsigned long long raw = qp[i];
        unsigned d = (unsigned)(raw >> 32);
        unsigned sb = (d * 512u) / N - (unsigned)q * 64u;
        atomicAdd(&hist[sb], 1);
    }
    __syncthreads();
    if (threadIdx.x < 64) l2c[((q * 64 + threadIdx.x) << 6) + j] = hist[threadIdx.x];
}

// ---------- 3d. level-2 partition: queue -> queue2 (sub-bin-grouped, packed) ----------
// queue2 entry: (dloc << 24) | src, dloc = d - first node of sub-bin
__global__ __launch_bounds__(256) void l2part_kernel(const uint2* __restrict__ queue,
                                                     const int* __restrict__ bbase,
                                                     const int* __restrict__ l2base,
                                                     unsigned* __restrict__ queue2, unsigned N,
                                                     int E, int nbp) {
    __shared__ int base[64];
    const int q = blockIdx.x & 7, j = blockIdx.x >> 3;
    const int bb0 = bbase[q * nbp];
    const int bb1 = (q == 7) ? E : bbase[(q + 1) * nbp];
    const int len = bb1 - bb0;
    const int cl = (len + 63) >> 6;
    const int c0 = min(bb0 + j * cl, bb1);
    const int c1 = min(c0 + cl, bb1);
    if (threadIdx.x < 64) base[threadIdx.x] = l2base[((q * 64 + threadIdx.x) << 6) + j];
    __syncthreads();
    const unsigned long long* qp = reinterpret_cast<const unsigned long long*>(queue);
    for (int i = c0 + threadIdx.x; i < c1; i += 256) {
        unsigned long long raw = qp[i];
        unsigned d = (unsigned)(raw >> 32);
        unsigned s = (unsigned)raw;
        unsigned g = (d * 512u) / N;
        unsigned v0g = (g * N + 511u) >> 9;
        int p = atomicAdd(&base[g - (unsigned)q * 64u], 1);
        queue2[p] = ((d - v0g) << 24) | s;
    }
}

// ---------- 3e. sub-bin counting sort -> csr + counts/cursor/dinv ----------
// grid 512, 1024 thr. g = (B&7)*64 + B>>3 keeps bucket on its XCD.
__global__ __launch_bounds__(1024) void subfill_kernel(const unsigned* __restrict__ queue2,
                                                       const int* __restrict__ l2base,
                                                       int* __restrict__ csr_src,
                                                       int* __restrict__ counts,
                                                       int* __restrict__ cursor,
                                                       float* __restrict__ dinv, unsigned N,
                                                       int E) {
    __shared__ int cnt[256];
    __shared__ int ofs[256];
    __shared__ int stage[8192];
    const int B = blockIdx.x;
    const int g = (B & 7) * 64 + (B >> 3);
    const int e0 = l2base[g << 6];
    const int e1 = (g == 511) ? E : l2base[(g + 1) << 6];
    const unsigned v0 = ((unsigned)g * N + 511u) >> 9;
    const unsigned v1 = min((((unsigned)g + 1u) * N + 511u) >> 9, N);
    const int nn = (int)(v1 - v0);
    const int tid = threadIdx.x;
    if (tid < 256) cnt[tid] = 0;
    __syncthreads();
    for (int i = e0 + tid; i < e1; i += 1024) atomicAdd(&cnt[queue2[i] >> 24], 1);
    __syncthreads();
    // inclusive scan of cnt into ofs (first 256 lanes)
    if (tid < 256) ofs[tid] = cnt[tid];
    __syncthreads();
    for (int off = 1; off < 256; off <<= 1) {
        int add = (tid < 256 && tid >= off) ? ofs[tid - off] : 0;
        __syncthreads();
        if (tid < 256) ofs[tid] += add;
        __syncthreads();
    }
    if (tid < nn) {
        int excl = ofs[tid] - cnt[tid];
        counts[v0 + tid] = cnt[tid];
        cursor[v0 + tid] = e0 + excl;
        dinv[v0 + tid] = rsqrtf((float)(cnt[tid] + 1));
    }
    __syncthreads();
    if (tid < 256) ofs[tid] -= cnt[tid];  // exclusive, used as running cursors
    __syncthreads();
    for (int i = e0 + tid; i < e1; i += 1024) {
        unsigned raw = queue2[i];
        int p = atomicAdd(&ofs[raw >> 24], 1);
        stage[p] = (int)(raw & 0xFFFFFFu);
    }
    __syncthreads();
    const int tot = e1 - e0;
    for (int t = tid; t < tot; t += 1024) csr_src[e0 + t] = stage[t];
}

// ---------- 4. MFMA GEMM: out = X[nrows,KD](f32) @ Wbf[c][k](bf16).T ----------
template <int KD, int MODE>
__global__ __launch_bounds__(256) void gemm_mfma(const float* __restrict__ X,
                                                 const unsigned short* __restrict__ Wbf,
                                                 const float* __restrict__ dinv,
                                                 const float* ADD,
                                                 unsigned short* __restrict__ out_bf,
                                                 float* out_f, int nrows) {
    __shared__ __align__(16) unsigned short ldsX[128 * 40];
    const int tid = threadIdx.x;
    const int w = tid >> 6;
    const int l = tid & 63;
    const int l16 = l & 15;
    const int kg = l >> 4;
    const int row0 = blockIdx.x * 128;

    f32x4 acc[2][8];
#pragma unroll
    for (int i = 0; i < 2; ++i)
#pragma unroll
        for (int j = 0; j < 8; ++j) acc[i][j] = (f32x4)(0.f);

    const int srow = tid >> 1;
    const int rload = min(row0 + srow, nrows - 1);
    const int kk0 = (tid & 1) * 16;
    const float* xrow = X + (size_t)rload * KD + kk0;

    for (int k0 = 0; k0 < KD; k0 += 32) {
        __syncthreads();
        {
            const float4* xs = reinterpret_cast<const float4*>(xrow + k0);
            float4 v0 = xs[0], v1 = xs[1], v2 = xs[2], v3 = xs[3];
            uint4 pa, pb;
            pa.x = pack2bf(v0.x, v0.y); pa.y = pack2bf(v0.z, v0.w);
            pa.z = pack2bf(v1.x, v1.y); pa.w = pack2bf(v1.z, v1.w);
            pb.x = pack2bf(v2.x, v2.y); pb.y = pack2bf(v2.z, v2.w);
            pb.z = pack2bf(v3.x, v3.y); pb.w = pack2bf(v3.z, v3.w);
            *reinterpret_cast<uint4*>(&ldsX[srow * 40 + kk0]) = pa;
            *reinterpret_cast<uint4*>(&ldsX[srow * 40 + kk0 + 8]) = pb;
        }
        __syncthreads();

        short8 a0 = *reinterpret_cast<const short8*>(&ldsX[(w * 32 + l16) * 40 + kg * 8]);
        short8 a1 = *reinterpret_cast<const short8*>(&ldsX[(w * 32 + 16 + l16) * 40 + kg * 8]);
#pragma unroll
        for (int ct = 0; ct < 8; ++ct) {
            short8 b = *reinterpret_cast<const short8*>(
                &Wbf[(size_t)(ct * 16 + l16) * KD + k0 + kg * 8]);
            acc[0][ct] = __builtin_amdgcn_mfma_f32_16x16x32_bf16(a0, b, acc[0][ct], 0, 0, 0);
            acc[1][ct] = __builtin_amdgcn_mfma_f32_16x16x32_bf16(a1, b, acc[1][ct], 0, 0, 0);
        }
    }

#pragma unroll
    for (int rt = 0; rt < 2; ++rt) {
        const int rbase = row0 + w * 32 + rt * 16 + kg * 4;
        float dv[4];
        if (MODE == 0) {
#pragma unroll
            for (int reg = 0; reg < 4; ++reg)
                dv[reg] = (rbase + reg < nrows) ? dinv[rbase + reg] : 0.f;
        }
#pragma unroll
        for (int ct = 0; ct < 8; ++ct) {
            const int col = ct * 16 + l16;
            f32x4 d = acc[rt][ct];
#pragma unroll
            for (int reg = 0; reg < 4; ++reg) {
                int r = rbase + reg;
                if (r < nrows) {
                    if (MODE == 0) {
                        out_bf[(size_t)r * 128 + col] = f2bf(d[reg] * dv[reg]);
                    } else {
                        float add = ADD[(size_t)r * 128 + col];
                        out_f[(size_t)r * 128 + col] = fmaxf(d[reg] + add, 0.f);
                    }
                }
            }
        }
    }
}

// ---------- 5. aggregation ----------
__global__ __launch_bounds__(256) void agg_kernel(const unsigned int* __restrict__ h,
                                                  const int* __restrict__ csr_src,
                                                  const int* __restrict__ cursor,
                                                  const int* __restrict__ counts,
                                                  const float* __restrict__ dinv,
                                                  float* __restrict__ agg, int n) {
    int v = blockIdx.x * 4 + (threadIdx.x >> 6);
    if (v >= n) return;
    const int lane = threadIdx.x & 63;
    const int eg = lane >> 4;
    const int c = lane & 15;
    const int cnt = counts[v];
    const int start = cursor[v];

    const uint4* hp = reinterpret_cast<const uint4*>(h);
    float acc[8];
#pragma unroll
    for (int j = 0; j < 8; ++j) acc[j] = 0.f;

    int s_next = (eg < cnt) ? csr_src[start + eg] : -1;
    for (int base = 0; base < cnt; base += 4) {
        int s = s_next;
        int nx = base + 4 + eg;
        s_next = (nx < cnt) ? csr_src[start + nx] : -1;
        if (s >= 0) {
            uint4 val = hp[(size_t)s * 16 + c];
            acc[0] += bflo(val.x); acc[1] += bfhi(val.x);
            acc[2] += bflo(val.y); acc[3] += bfhi(val.y);
            acc[4] += bflo(val.z); acc[5] += bfhi(val.z);
            acc[6] += bflo(val.w); acc[7] += bfhi(val.w);
        }
    }
    if (eg == 0) {
        uint4 val = hp[(size_t)v * 16 + c];
        acc[0] += bflo(val.x); acc[1] += bfhi(val.x);
        acc[2] += bflo(val.y); acc[3] += bfhi(val.y);
        acc[4] += bflo(val.z); acc[5] += bfhi(val.z);
        acc[6] += bflo(val.w); acc[7] += bfhi(val.w);
    }
#pragma unroll
    for (int j = 0; j < 8; ++j) {
        acc[j] += __shfl_xor(acc[j], 16);
        acc[j] += __shfl_xor(acc[j], 32);
    }
    if (eg == 0) {
        float dv = dinv[v];
        float4 o0 = {acc[0] * dv, acc[1] * dv, acc[2] * dv, acc[3] * dv};
        float4 o1 = {acc[4] * dv, acc[5] * dv, acc[6] * dv, acc[7] * dv};
        *reinterpret_cast<float4*>(&agg[(size_t)v * 128 + c * 8]) = o0;
        *reinterpret_cast<float4*>(&agg[(size_t)v * 128 + c * 8 + 4]) = o1;
    }
}

// ---------- launch ----------
extern "C" void kernel_launch(void* const* d_in, const int* in_sizes, int n_in,
                              void* d_out, int out_size, void* d_ws, size_t ws_size,
                              hipStream_t stream) {
    const float* features = (const float*)d_in[0];
    const int*   edge     = (const int*)d_in[1];
    const float* emb      = (const float*)d_in[2];
    const float* Wconv    = (const float*)d_in[3];
    const float* Wmlp     = (const float*)d_in[4];
    float* out = (float*)d_out;

    const int N = in_sizes[0] / 256;
    const int E = in_sizes[1] / 2;
    const int* src = edge;
    const int* dst = edge + E;
    const int NBP = 4096;
    const int chunk = (E + NBP - 1) / NBP;

    char* ws = (char*)d_ws;
    size_t o = 0;
    auto take = [&](size_t b) {
        size_t cur = o;
        o += (b + 255) & ~(size_t)255;
        return cur;
    };
    unsigned short* Wp_bf   = (unsigned short*)(ws + take((size_t)128 * 128 * 2));
    unsigned short* Wm_bf   = (unsigned short*)(ws + take((size_t)128 * 256 * 2));
    int*            counts  = (int*)(ws + take((size_t)N * 4));
    int*            cursor  = (int*)(ws + take((size_t)N * 4));
    float*          dinv    = (float*)(ws + take((size_t)N * 4));
    int*            bc      = (int*)(ws + take((size_t)8 * NBP * 4));
    int*            bbase   = (int*)(ws + take((size_t)8 * NBP * 4));
    int*            l2c     = (int*)(ws + take((size_t)512 * 64 * 4));
    int*            l2base  = (int*)(ws + take((size_t)512 * 64 * 4));
    int*            csr_src = (int*)(ws + take((size_t)E * 4));
    unsigned*       queue2  = (unsigned*)(ws + take((size_t)E * 4));
    // queue1 (E uint2) and hbuf (N*128 bf16) share storage: queue1 dead after
    // l2part; gemm_mfma<128,0> (writes hbuf) runs after subfill.
    size_t qbytes = (size_t)E * 8;
    size_t hbytes = (size_t)N * 128 * 2;
    char*  qh     = ws + take(qbytes > hbytes ? qbytes : hbytes);
    uint2*          queue = (uint2*)qh;
    unsigned short* hbuf  = (unsigned short*)qh;
    (void)ws_size; (void)n_in; (void)out_size;

    hipLaunchKernelGGL(proj_kernel, dim3(128), dim3(128), 0, stream, Wconv, Wp_bf);
    hipLaunchKernelGGL(convw_kernel, dim3((128 * 256 + 255) / 256), dim3(256), 0, stream, Wmlp,
                       Wm_bf, 128 * 256);
    // level-1: 8 XCD-owned dst buckets
    hipLaunchKernelGGL(qcount_kernel, dim3(NBP), dim3(64), 0, stream, dst, bc, E, (unsigned)N,
                       chunk, NBP);
    hipLaunchKernelGGL(scan_kernel, dim3(1), dim3(1024), 0, stream, bc, bbase, 8 * NBP);
    hipLaunchKernelGGL(qpart_kernel, dim3(NBP), dim3(64), 0, stream, src, dst, bbase, queue, E,
                       (unsigned)N, chunk, NBP);
    // level-2: 512 sub-bins, XCD-local
    hipLaunchKernelGGL(l2count_kernel, dim3(512), dim3(256), 0, stream, queue, bbase, l2c,
                       (unsigned)N, E, NBP);
    hipLaunchKernelGGL(scan_kernel, dim3(1), dim3(1024), 0, stream, l2c, l2base, 512 * 64);
    hipLaunchKernelGGL(l2part_kernel, dim3(512), dim3(256), 0, stream, queue, bbase, l2base,
                       queue2, (unsigned)N, E, NBP);
    // sub-bin counting sort -> csr + counts/cursor/dinv (no global atomics)
    hipLaunchKernelGGL(subfill_kernel, dim3(512), dim3(1024), 0, stream, queue2, l2base, csr_src,
                       counts, cursor, dinv, (unsigned)N, E);
    // h' = bf16( dinv[row] * (emb @ Wp.T) )  -- overwrites queue1 storage
    hipLaunchKernelGGL((gemm_mfma<128, 0>), dim3((N + 127) / 128), dim3(256), 0, stream, emb,
                       Wp_bf, dinv, (const float*)nullptr, hbuf, (float*)nullptr, N);
    hipLaunchKernelGGL(agg_kernel, dim3((N + 3) / 4), dim3(256), 0, stream,
                       (const unsigned int*)hbuf, csr_src, cursor, counts, dinv, out, N);
    // out = relu(features @ Wmlp.T + agg)
    hipLaunchKernelGGL((gemm_mfma<256, 1>), dim3((N + 127) / 128), dim3(256), 0, stream, features,
                       Wm_bf, (const float*)nullptr, out, (unsigned short*)nullptr, out, N);
}

// Round 8
// 251.158 us; speedup vs baseline: 4.3235x; 1.7193x over previous
//
#include <hip/hip_runtime.h>

#define KAPPA 0.95f

typedef __attribute__((ext_vector_type(8))) short short8;
typedef __attribute__((ext_vector_type(4))) float f32x4;
typedef __attribute__((ext_vector_type(2))) float f32x2;

// ---------- bf16 helpers ----------
static __device__ inline unsigned short f2bf(float f) {
    unsigned int u = __float_as_uint(f);
    unsigned int rounding = 0x7fffu + ((u >> 16) & 1u);
    u += rounding;
    return (unsigned short)(u >> 16);
}
static __device__ inline unsigned int pack2bf(float x, float y) {
    return (unsigned int)f2bf(x) | ((unsigned int)f2bf(y) << 16);
}

#define H_SCALE 4096.0f

// ---------- 1. proj_norm_inf on W_conv -> bf16 row-major [c][k] ----------
__global__ __launch_bounds__(128) void proj_kernel(const float* __restrict__ W,
                                                   unsigned short* __restrict__ Wp_bf) {
    const int r = blockIdx.x;
    const int tid = threadIdx.x;
    __shared__ float s[128];
    __shared__ float c[128];
    __shared__ int rho_s;

    const float w = W[r * 128 + tid];
    const float a = fabsf(w);
    s[tid] = a;
    if (tid == 0) rho_s = 0;
    __syncthreads();

    for (int k = 2; k <= 128; k <<= 1) {
        for (int j = k >> 1; j > 0; j >>= 1) {
            int ixj = tid ^ j;
            if (ixj > tid) {
                bool up = ((tid & k) == 0);
                float x = s[tid], y = s[ixj];
                if ((x > y) == up) { s[tid] = y; s[ixj] = x; }
            }
            __syncthreads();
        }
    }

    const float u = s[127 - tid];
    c[tid] = u;
    __syncthreads();
    for (int off = 1; off < 128; off <<= 1) {
        float add = (tid >= off) ? c[tid - off] : 0.f;
        __syncthreads();
        c[tid] += add;
        __syncthreads();
    }
    const float rowsum = c[127];
    const float css = c[tid] - KAPPA;
    if (u - css / (float)(tid + 1) > 0.f) atomicAdd(&rho_s, 1);
    __syncthreads();

    float out = w;
    if (rowsum > KAPPA) {
        int rho = max(rho_s, 1);
        float theta = (c[rho - 1] - KAPPA) / (float)rho;
        float m = fmaxf(a - theta, 0.f);
        out = (w > 0.f) ? m : ((w < 0.f) ? -m : 0.f);
    }
    Wp_bf[r * 128 + tid] = f2bf(out);  // row-major [c][k]
}

// ---------- 2. W_mlp f32 -> bf16 ----------
__global__ void convw_kernel(const float* __restrict__ Wm, unsigned short* __restrict__ Wbf,
                             int n) {
    int i = blockIdx.x * blockDim.x + threadIdx.x;
    if (i < n) Wbf[i] = f2bf(Wm[i]);
}

// ---------- 3a. 512-bin histogram per chunk (LDS, atomic-free globally) ----------
__global__ __launch_bounds__(256) void rhist_kernel(const int* __restrict__ dst,
                                                    int* __restrict__ l2c, int E, unsigned N,
                                                    int chunk) {
    __shared__ int hist[512];
    const int b = blockIdx.x;
    const int i0 = b * chunk;
    const int i1 = min(i0 + chunk, E);
    for (int t = threadIdx.x; t < 512; t += 256) hist[t] = 0;
    __syncthreads();
    for (int i = i0 + threadIdx.x; i < i1; i += 256) {
        unsigned g = ((unsigned)dst[i] * 512u) / N;
        atomicAdd(&hist[g], 1);
    }
    __syncthreads();
    for (int t = threadIdx.x; t < 512; t += 256) l2c[(t << 9) | b] = hist[t];  // [g][chunk]
}

// ---------- 3b. hierarchical scan of l2c (512x512) ----------
__global__ __launch_bounds__(256) void rsum_kernel(const int* __restrict__ l2c,
                                                   int* __restrict__ R) {
    __shared__ int tmp[256];
    const int g = blockIdx.x;
    int s = 0;
    for (int j = threadIdx.x; j < 512; j += 256) s += l2c[(g << 9) | j];
    tmp[threadIdx.x] = s;
    __syncthreads();
    for (int off = 128; off > 0; off >>= 1) {
        if (threadIdx.x < off) tmp[threadIdx.x] += tmp[threadIdx.x + off];
        __syncthreads();
    }
    if (threadIdx.x == 0) R[g] = tmp[0];
}

__global__ __launch_bounds__(512) void rscan_kernel(const int* __restrict__ R,
                                                    int* __restrict__ Gbase) {
    __shared__ int tmp[512];
    const int tid = threadIdx.x;
    int v = R[tid];
    tmp[tid] = v;
    __syncthreads();
    int val = v;
    for (int off = 1; off < 512; off <<= 1) {
        int add = (tid >= off) ? tmp[tid - off] : 0;
        __syncthreads();
        val += add;
        tmp[tid] = val;
        __syncthreads();
    }
    Gbase[tid] = val - v;  // exclusive
}

__global__ __launch_bounds__(512) void rowscan_kernel(const int* __restrict__ l2c,
                                                      const int* __restrict__ Gbase,
                                                      int* __restrict__ l2base) {
    __shared__ int tmp[512];
    const int g = blockIdx.x;
    const int tid = threadIdx.x;
    int v = l2c[(g << 9) | tid];
    tmp[tid] = v;
    __syncthreads();
    int val = v;
    for (int off = 1; off < 512; off <<= 1) {
        int add = (tid >= off) ? tmp[tid - off] : 0;
        __syncthreads();
        val += add;
        tmp[tid] = val;
        __syncthreads();
    }
    l2base[(g << 9) | tid] = Gbase[g] + val - v;
}

// ---------- 3c. partition: edges -> queue2 ((dloc<<24)|src), bin-grouped ----------
__global__ __launch_bounds__(256) void rpart_kernel(const int* __restrict__ src,
                                                    const int* __restrict__ dst,
                                                    const int* __restrict__ l2base,
                                                    unsigned* __restrict__ queue2, int E,
                                                    unsigned N, int chunk) {
    __shared__ int base[512];
    const int b = blockIdx.x;
    const int i0 = b * chunk;
    const int i1 = min(i0 + chunk, E);
    for (int t = threadIdx.x; t < 512; t += 256) base[t] = l2base[(t << 9) | b];
    __syncthreads();
    for (int i = i0 + threadIdx.x; i < i1; i += 256) {
        unsigned d = (unsigned)dst[i];
        unsigned s = (unsigned)src[i];
        unsigned g = (d * 512u) / N;
        unsigned v0g = (g * N + 511u) >> 9;
        int p = atomicAdd(&base[g], 1);
        queue2[p] = ((d - v0g) << 24) | s;
    }
}

// ---------- 3d. sub-bin counting sort -> csr + counts/cursor/dinv ----------
__global__ __launch_bounds__(1024) void subfill_kernel(const unsigned* __restrict__ queue2,
                                                       const int* __restrict__ Gbase,
                                                       int* __restrict__ csr_src,
                                                       int* __restrict__ counts,
                                                       int* __restrict__ cursor,
                                                       float* __restrict__ dinv, unsigned N,
                                                       int E) {
    __shared__ int cnt[256];
    __shared__ int ofs[256];
    __shared__ int stage[8192];
    const int B = blockIdx.x;
    const int g = (B & 7) * 64 + (B >> 3);
    const int e0 = Gbase[g];
    const int e1 = (g == 511) ? E : Gbase[g + 1];
    const unsigned v0 = ((unsigned)g * N + 511u) >> 9;
    const unsigned v1 = min((((unsigned)g + 1u) * N + 511u) >> 9, N);
    const int nn = (int)(v1 - v0);
    const int tid = threadIdx.x;
    if (tid < 256) cnt[tid] = 0;
    __syncthreads();
    for (int i = e0 + tid; i < e1; i += 1024) atomicAdd(&cnt[queue2[i] >> 24], 1);
    __syncthreads();
    if (tid < 256) ofs[tid] = cnt[tid];
    __syncthreads();
    for (int off = 1; off < 256; off <<= 1) {
        int add = (tid < 256 && tid >= off) ? ofs[tid - off] : 0;
        __syncthreads();
        if (tid < 256) ofs[tid] += add;
        __syncthreads();
    }
    if (tid < nn) {
        int excl = ofs[tid] - cnt[tid];
        counts[v0 + tid] = cnt[tid];
        cursor[v0 + tid] = e0 + excl;
        dinv[v0 + tid] = rsqrtf((float)(cnt[tid] + 1));
    }
    __syncthreads();
    if (tid < 256) ofs[tid] -= cnt[tid];
    __syncthreads();
    for (int i = e0 + tid; i < e1; i += 1024) {
        unsigned raw = queue2[i];
        int p = atomicAdd(&ofs[raw >> 24], 1);
        stage[p] = (int)(raw & 0xFFFFFFu);
    }
    __syncthreads();
    const int tot = e1 - e0;
    for (int t = tid; t < tot; t += 1024) csr_src[e0 + t] = stage[t];
}

// ---------- 4. MFMA GEMM (A=W, B=X): out[r][c], lane owns 1 row x 4 consecutive cols ----------
// MODE 0: h8[r] = fp8( dinv[r]*H_SCALE * acc )   MODE 1: out_f = relu(acc + ADD)
template <int KD, int MODE>
__global__ __launch_bounds__(256) void gemm_mfma(const float* __restrict__ X,
                                                 const unsigned short* __restrict__ Wbf,
                                                 const float* __restrict__ dinv,
                                                 const float* ADD,
                                                 unsigned int* __restrict__ out_u32,
                                                 float* out_f, int nrows) {
    __shared__ __align__(16) unsigned short ldsX[128 * 40];
    const int tid = threadIdx.x;
    const int w = tid >> 6;
    const int l = tid & 63;
    const int l16 = l & 15;
    const int kg = l >> 4;  // k-chunk in mainloop; col-group in epilogue
    const int row0 = blockIdx.x * 128;

    f32x4 acc[2][8];
#pragma unroll
    for (int i = 0; i < 2; ++i)
#pragma unroll
        for (int j = 0; j < 8; ++j) acc[i][j] = (f32x4)(0.f);

    const int srow = tid >> 1;
    const int rload = min(row0 + srow, nrows - 1);
    const int kk0 = (tid & 1) * 16;
    const float* xrow = X + (size_t)rload * KD + kk0;

    for (int k0 = 0; k0 < KD; k0 += 32) {
        __syncthreads();
        {
            const float4* xs = reinterpret_cast<const float4*>(xrow + k0);
            float4 v0 = xs[0], v1 = xs[1], v2 = xs[2], v3 = xs[3];
            uint4 pa, pb;
            pa.x = pack2bf(v0.x, v0.y); pa.y = pack2bf(v0.z, v0.w);
            pa.z = pack2bf(v1.x, v1.y); pa.w = pack2bf(v1.z, v1.w);
            pb.x = pack2bf(v2.x, v2.y); pb.y = pack2bf(v2.z, v2.w);
            pb.z = pack2bf(v3.x, v3.y); pb.w = pack2bf(v3.z, v3.w);
            *reinterpret_cast<uint4*>(&ldsX[srow * 40 + kk0]) = pa;
            *reinterpret_cast<uint4*>(&ldsX[srow * 40 + kk0 + 8]) = pb;
        }
        __syncthreads();

        short8 x0 = *reinterpret_cast<const short8*>(&ldsX[(w * 32 + l16) * 40 + kg * 8]);
        short8 x1 = *reinterpret_cast<const short8*>(&ldsX[(w * 32 + 16 + l16) * 40 + kg * 8]);
#pragma unroll
        for (int ct = 0; ct < 8; ++ct) {
            short8 wv = *reinterpret_cast<const short8*>(
                &Wbf[(size_t)(ct * 16 + l16) * KD + k0 + kg * 8]);
            // A = W (M=cols), B = X (N=rows): D col=lane&15 -> row, D row -> col
            acc[0][ct] = __builtin_amdgcn_mfma_f32_16x16x32_bf16(wv, x0, acc[0][ct], 0, 0, 0);
            acc[1][ct] = __builtin_amdgcn_mfma_f32_16x16x32_bf16(wv, x1, acc[1][ct], 0, 0, 0);
        }
    }

#pragma unroll
    for (int rt = 0; rt < 2; ++rt) {
        const int row = row0 + w * 32 + rt * 16 + l16;
        if (row < nrows) {
            if (MODE == 0) {
                const float dv = dinv[row] * H_SCALE;
#pragma unroll
                for (int ct = 0; ct < 8; ++ct) {
                    f32x4 d = acc[rt][ct];
                    unsigned lo =
                        __builtin_amdgcn_cvt_pk_fp8_f32(d[0] * dv, d[1] * dv, 0u, false);
                    unsigned hi =
                        __builtin_amdgcn_cvt_pk_fp8_f32(d[2] * dv, d[3] * dv, lo, true);
                    out_u32[(size_t)row * 32 + ct * 4 + kg] = hi;
                }
            } else {
#pragma unroll
                for (int ct = 0; ct < 8; ++ct) {
                    f32x4 d = acc[rt][ct];
                    const float4 a =
                        *reinterpret_cast<const float4*>(&ADD[(size_t)row * 128 + ct * 16 + kg * 4]);
                    float4 o;
                    o.x = fmaxf(d[0] + a.x, 0.f);
                    o.y = fmaxf(d[1] + a.y, 0.f);
                    o.z = fmaxf(d[2] + a.z, 0.f);
                    o.w = fmaxf(d[3] + a.w, 0.f);
                    *reinterpret_cast<float4*>(&out_f[(size_t)row * 128 + ct * 16 + kg * 4]) = o;
                }
            }
        }
    }
}

// ---------- 5. aggregation over fp8 h' ----------
static __device__ inline void unp8(float* acc, unsigned wv, int off) {
    f32x2 lo = __builtin_amdgcn_cvt_pk_f32_fp8(wv, false);
    f32x2 hi = __builtin_amdgcn_cvt_pk_f32_fp8(wv, true);
    acc[off + 0] += lo[0];
    acc[off + 1] += lo[1];
    acc[off + 2] += hi[0];
    acc[off + 3] += hi[1];
}

__global__ __launch_bounds__(256) void agg_kernel(const uint4* __restrict__ h8,
                                                  const int* __restrict__ csr_src,
                                                  const int* __restrict__ cursor,
                                                  const int* __restrict__ counts,
                                                  const float* __restrict__ dinv,
                                                  float* __restrict__ agg, int n) {
    int v = blockIdx.x * 4 + (threadIdx.x >> 6);
    if (v >= n) return;
    const int lane = threadIdx.x & 63;
    const int eg = lane >> 3;  // 8 edge slots
    const int c = lane & 7;    // 16 features each (one uint4 of fp8)
    const int cnt = counts[v];
    const int start = cursor[v];

    float acc[16];
#pragma unroll
    for (int j = 0; j < 16; ++j) acc[j] = 0.f;

    int s_next = (eg < cnt) ? csr_src[start + eg] : -1;
    for (int base = 0; base < cnt; base += 8) {
        int s = s_next;
        int nx = base + 8 + eg;
        s_next = (nx < cnt) ? csr_src[start + nx] : -1;
        if (s >= 0) {
            uint4 val = h8[(size_t)s * 8 + c];
            unp8(acc, val.x, 0);
            unp8(acc, val.y, 4);
            unp8(acc, val.z, 8);
            unp8(acc, val.w, 12);
        }
    }
    if (eg == 0) {  // self loop
        uint4 val = h8[(size_t)v * 8 + c];
        unp8(acc, val.x, 0);
        unp8(acc, val.y, 4);
        unp8(acc, val.z, 8);
        unp8(acc, val.w, 12);
    }
#pragma unroll
    for (int j = 0; j < 16; ++j) {
        acc[j] += __shfl_xor(acc[j], 8);
        acc[j] += __shfl_xor(acc[j], 16);
        acc[j] += __shfl_xor(acc[j], 32);
    }
    if (eg == 0) {
        const float dv = dinv[v] * (1.0f / H_SCALE);
#pragma unroll
        for (int k = 0; k < 4; ++k) {
            float4 o = {acc[4 * k] * dv, acc[4 * k + 1] * dv, acc[4 * k + 2] * dv,
                        acc[4 * k + 3] * dv};
            *reinterpret_cast<float4*>(&agg[(size_t)v * 128 + c * 16 + k * 4]) = o;
        }
    }
}

// ---------- launch ----------
extern "C" void kernel_launch(void* const* d_in, const int* in_sizes, int n_in,
                              void* d_out, int out_size, void* d_ws, size_t ws_size,
                              hipStream_t stream) {
    const float* features = (const float*)d_in[0];
    const int*   edge     = (const int*)d_in[1];
    const float* emb      = (const float*)d_in[2];
    const float* Wconv    = (const float*)d_in[3];
    const float* Wmlp     = (const float*)d_in[4];
    float* out = (float*)d_out;

    const int N = in_sizes[0] / 256;
    const int E = in_sizes[1] / 2;
    const int* src = edge;
    const int* dst = edge + E;
    const int chunk = (E + 511) / 512;

    char* ws = (char*)d_ws;
    size_t o = 0;
    auto take = [&](size_t b) {
        size_t cur = o;
        o += (b + 255) & ~(size_t)255;
        return cur;
    };
    unsigned short* Wp_bf   = (unsigned short*)(ws + take((size_t)128 * 128 * 2));
    unsigned short* Wm_bf   = (unsigned short*)(ws + take((size_t)128 * 256 * 2));
    int*            counts  = (int*)(ws + take((size_t)N * 4));
    int*            cursor  = (int*)(ws + take((size_t)N * 4));
    float*          dinv    = (float*)(ws + take((size_t)N * 4));
    int*            l2c     = (int*)(ws + take((size_t)512 * 512 * 4));
    int*            l2base  = (int*)(ws + take((size_t)512 * 512 * 4));
    int*            R       = (int*)(ws + take((size_t)512 * 4));
    int*            Gbase   = (int*)(ws + take((size_t)512 * 4));
    int*            csr_src = (int*)(ws + take((size_t)E * 4));
    // queue2 (E u32) aliases fp8 h-table (N*128 B): queue2 consumed by subfill
    // before gemm0 writes h8 (stream-serialized).
    size_t qbytes = (size_t)E * 4;
    size_t hbytes = (size_t)N * 128;
    char*  qh     = ws + take(qbytes > hbytes ? qbytes : hbytes);
    unsigned*     queue2 = (unsigned*)qh;
    unsigned int* h8     = (unsigned int*)qh;
    (void)ws_size; (void)n_in; (void)out_size;

    hipLaunchKernelGGL(proj_kernel, dim3(128), dim3(128), 0, stream, Wconv, Wp_bf);
    hipLaunchKernelGGL(convw_kernel, dim3((128 * 256 + 255) / 256), dim3(256), 0, stream, Wmlp,
                       Wm_bf, 128 * 256);
    // 512-bin radix partition (one level, global-atomic-free)
    hipLaunchKernelGGL(rhist_kernel, dim3(512), dim3(256), 0, stream, dst, l2c, E, (unsigned)N,
                       chunk);
    hipLaunchKernelGGL(rsum_kernel, dim3(512), dim3(256), 0, stream, l2c, R);
    hipLaunchKernelGGL(rscan_kernel, dim3(1), dim3(512), 0, stream, R, Gbase);
    hipLaunchKernelGGL(rowscan_kernel, dim3(512), dim3(512), 0, stream, l2c, Gbase, l2base);
    hipLaunchKernelGGL(rpart_kernel, dim3(512), dim3(256), 0, stream, src, dst, l2base, queue2, E,
                       (unsigned)N, chunk);
    // sub-bin counting sort -> csr + counts/cursor/dinv
    hipLaunchKernelGGL(subfill_kernel, dim3(512), dim3(1024), 0, stream, queue2, Gbase, csr_src,
                       counts, cursor, dinv, (unsigned)N, E);
    // h8 = fp8( dinv[row]*4096 * (emb @ Wp.T) )  -- overwrites queue2 storage
    hipLaunchKernelGGL((gemm_mfma<128, 0>), dim3((N + 127) / 128), dim3(256), 0, stream, emb,
                       Wp_bf, dinv, (const float*)nullptr, h8, (float*)nullptr, N);
    hipLaunchKernelGGL(agg_kernel, dim3((N + 3) / 4), dim3(256), 0, stream, (const uint4*)h8,
                       csr_src, cursor, counts, dinv, out, N);
    // out = relu(features @ Wmlp.T + agg)
    hipLaunchKernelGGL((gemm_mfma<256, 1>), dim3((N + 127) / 128), dim3(256), 0, stream, features,
                       Wm_bf, (const float*)nullptr, out, (unsigned int*)nullptr, out, N);
}